// Round 6
// baseline (1557.874 us; speedup 1.0000x reference)
//
#include <hip/hip_runtime.h>
#include <math.h>

#define BATCH 8
#define NPER 2048
#define NPTS (BATCH*NPER)   // 16384
#define KNN 30

typedef __attribute__((ext_vector_type(8))) short bf16x8;
typedef __attribute__((ext_vector_type(4))) float f32x4;

__device__ __forceinline__ ushort f2bf(float x) {
    unsigned u = __float_as_uint(x);
    unsigned r = (u + 0x7fffu + ((u >> 16) & 1u)) >> 16;
    return (ushort)r;
}
__device__ __forceinline__ float bf2f(ushort h) {
    return __uint_as_float(((unsigned)h) << 16);
}

// ---------------- concat x,pos -> x0 (NPTS x 6) ----------------
__global__ void concat_kernel(const float* __restrict__ x, const float* __restrict__ pos,
                              float* __restrict__ x0) {
    int n = blockIdx.x * blockDim.x + threadIdx.x;
    if (n >= NPTS) return;
#pragma unroll
    for (int d = 0; d < 3; ++d) {
        x0[n*6 + d]     = x[n*3 + d];
        x0[n*6 + 3 + d] = pos[n*3 + d];
    }
}

// ---------------- squared norms ----------------
template<int D>
__global__ void d2_kernel(const float* __restrict__ f, int stride, float* __restrict__ d2) {
    int n = blockIdx.x * blockDim.x + threadIdx.x;
    if (n >= NPTS) return;
    const float* r = f + (size_t)n * stride;
    float s = 0.f;
#pragma unroll
    for (int d = 0; d < D; ++d) s += r[d]*r[d];
    d2[n] = s;
}

// ---------------- kNN v3: register-resident. Wave owns 4 queries; lane owns candidates
// ---------------- lane+64i. Queries broadcast from LDS per 16-dim chunk. No sdist LDS. ----
template<int D>
__global__ __launch_bounds__(256, 2) void knn_reg_kernel(const float* __restrict__ f, int stride,
                                                         const float* __restrict__ d2,
                                                         int* __restrict__ idx) {
    __shared__ float sq[16][(D+7)/8*8];
    __shared__ float sd2n[16];
    int t = threadIdx.x;
    int n0 = blockIdx.x * 16;
    int base = (n0 >> 11) << 11;          // batch start (16 consecutive pts same batch)

    for (int i = t; i < 16*D; i += 256) {
        int q = i / D, d = i - q*D;
        sq[q][d] = f[(size_t)(n0 + q)*stride + d];
    }
    if (t < 16) sd2n[t] = d2[n0 + t];
    __syncthreads();

    int w = t >> 6, lane = t & 63;
    int q0 = 4*w;

    float acc[4][32];
#pragma unroll
    for (int q = 0; q < 4; ++q)
#pragma unroll
        for (int i = 0; i < 32; ++i) acc[q][i] = 0.f;

    if constexpr (D % 16 == 0) {
#pragma unroll 1
        for (int c = 0; c < D/16; ++c) {
            int d0 = c*16;
            float4 qv[4][4];
#pragma unroll
            for (int q = 0; q < 4; ++q)
#pragma unroll
                for (int g = 0; g < 4; ++g)
                    qv[q][g] = *reinterpret_cast<const float4*>(&sq[q0+q][d0 + 4*g]);
#pragma unroll 2
            for (int i = 0; i < 32; ++i) {
                const float* cp = f + (size_t)(base + lane + 64*i)*stride + d0;
                float4 a0 = *reinterpret_cast<const float4*>(cp);
                float4 a1 = *reinterpret_cast<const float4*>(cp + 4);
                float4 a2 = *reinterpret_cast<const float4*>(cp + 8);
                float4 a3 = *reinterpret_cast<const float4*>(cp + 12);
#pragma unroll
                for (int q = 0; q < 4; ++q) {
                    acc[q][i] += a0.x*qv[q][0].x + a0.y*qv[q][0].y + a0.z*qv[q][0].z + a0.w*qv[q][0].w;
                    acc[q][i] += a1.x*qv[q][1].x + a1.y*qv[q][1].y + a1.z*qv[q][1].z + a1.w*qv[q][1].w;
                    acc[q][i] += a2.x*qv[q][2].x + a2.y*qv[q][2].y + a2.z*qv[q][2].z + a2.w*qv[q][2].w;
                    acc[q][i] += a3.x*qv[q][3].x + a3.y*qv[q][3].y + a3.z*qv[q][3].z + a3.w*qv[q][3].w;
                }
            }
        }
    } else {
        float qv[4][D];
#pragma unroll
        for (int q = 0; q < 4; ++q)
#pragma unroll
            for (int d = 0; d < D; ++d) qv[q][d] = sq[q0+q][d];
#pragma unroll 2
        for (int i = 0; i < 32; ++i) {
            const float* cp = f + (size_t)(base + lane + 64*i)*stride;
            float cv[D];
#pragma unroll
            for (int d = 0; d < D; ++d) cv[d] = cp[d];
#pragma unroll
            for (int q = 0; q < 4; ++q) {
#pragma unroll
                for (int d = 0; d < D; ++d) acc[q][i] += cv[d]*qv[q][d];
            }
        }
    }

    // ---- per-query selection: identical radix-2 semantics as before ----
#pragma unroll
    for (int q = 0; q < 4; ++q) {
        int n = n0 + q0 + q;
        float dn = sd2n[q0 + q];
        unsigned u[32];
#pragma unroll
        for (int i = 0; i < 32; ++i) {
            float dm = d2[base + lane + 64*i];
            float dv = dn + dm - 2.f*acc[q][i];
            int b = __float_as_int(dv);
            u[i] = (unsigned)(b ^ ((b >> 31) | 0x80000000));
        }

        unsigned T = 0u;
#pragma unroll
        for (int bit = 31; bit >= 0; --bit) {
            unsigned C = T | (1u << bit);
            int c = 0;
#pragma unroll
            for (int i = 0; i < 32; ++i) c += (u[i] < C) ? 1 : 0;
#pragma unroll
            for (int off = 1; off < 64; off <<= 1) c += __shfl_xor(c, off);
            if (c < KNN) T = C;
        }

        unsigned lm = 0u, em = 0u;
#pragma unroll
        for (int i = 0; i < 32; ++i) {
            lm |= (u[i] < T)  ? (1u << i) : 0u;
            em |= (u[i] == T) ? (1u << i) : 0u;
        }
        int nl = __popc(lm);
        int inc = nl;
#pragma unroll
        for (int off = 1; off < 64; off <<= 1) {
            int y = __shfl_up(inc, off);
            if (lane >= off) inc += y;
        }
        int excl = inc - nl;
        int total_less = __shfl(inc, 63);

        int* op = idx + (size_t)n * KNN;
        int slot = excl;
#pragma unroll
        for (int i = 0; i < 32; ++i) {
            if (lm & (1u << i)) { op[slot] = base + i*64 + lane; ++slot; }
        }

        int need = KNN - total_less;
        int running = 0;
#pragma unroll
        for (int i = 0; i < 32; ++i) {
            unsigned long long bal = __ballot((em >> i) & 1u);
            if (bal) {
                unsigned long long lt = bal & ((1ull << lane) - 1ull);
                int r = running + __popcll(lt);
                if (((em >> i) & 1u) && r < need) op[total_less + r] = base + i*64 + lane;
                running += (int)__popcll(bal);
            }
        }
    }
}

// ---------------- G = F @ waB  (waB = rows D..2D-1 of wa), G is [NPTS][64] ----------------
template<int D>
__global__ __launch_bounds__(256) void gmat_kernel(const float* __restrict__ fin, int in_stride,
                                                   const float* __restrict__ wa,
                                                   float* __restrict__ G) {
    constexpr int DP = (D+3)/4*4;
    __shared__ float sF[64][DP];
    int t = threadIdx.x;
    int row0 = blockIdx.x * 64;
    for (int i = t; i < 64*D; i += 256) {
        int r = i / D, c = i - r*D;
        sF[r][c] = fin[(size_t)(row0 + r)*in_stride + c];
    }
    int w = t >> 6, lane = t & 63;
    float wreg[D];
#pragma unroll
    for (int d = 0; d < D; ++d) wreg[d] = wa[(size_t)(D + d)*64 + lane];
    __syncthreads();
#pragma unroll 1
    for (int pi = 0; pi < 16; ++pi) {
        int p = w*16 + pi;
        float acc = 0.f;
        if constexpr (D % 4 == 0) {
#pragma unroll
            for (int d = 0; d < D; d += 4) {
                float4 fv = *reinterpret_cast<const float4*>(&sF[p][d]);
                acc += fv.x*wreg[d] + fv.y*wreg[d+1] + fv.z*wreg[d+2] + fv.w*wreg[d+3];
            }
        } else {
#pragma unroll
            for (int d = 0; d < D; ++d) acc += sF[p][d]*wreg[d];
        }
        G[(size_t)(row0 + p)*64 + lane] = acc;
    }
}

// ---------------- EdgeConv v2: h1 = relu(base + G[j]); h2 = h1@wb; max over j ----------------
template<int D>
__global__ __launch_bounds__(256) void edgeconv2_kernel(const float* __restrict__ fin, int in_stride,
                                const float* __restrict__ G,
                                const int* __restrict__ idx,
                                const float* __restrict__ wa, const float* __restrict__ ba,
                                const float* __restrict__ wb, const float* __restrict__ bb,
                                float* __restrict__ fout, int out_stride) {
    __shared__ float sxi[4][(D+3)/4*4];
    __shared__ float sh1[4][2][64];
    int t = threadIdx.x;
    int w = t >> 6, lane = t & 63;
    int n = blockIdx.x * 4 + w;

    float wbc[64];
#pragma unroll
    for (int k = 0; k < 64; ++k) wbc[k] = wb[(size_t)k*64 + lane];
    float bbc = bb[lane];

    if (lane < D) sxi[w][lane] = fin[(size_t)n * in_stride + lane];
    __syncthreads();

    float basec = ba[lane];
#pragma unroll
    for (int d = 0; d < D; ++d)
        basec += sxi[w][d] * (wa[(size_t)d*64 + lane] - wa[(size_t)(D + d)*64 + lane]);

    const int* ip = idx + (size_t)n * KNN;
    int2 jp = *reinterpret_cast<const int2*>(ip);
    float g0 = G[(size_t)jp.x*64 + lane];
    float g1 = G[(size_t)jp.y*64 + lane];
    float maxv = -3.4e38f;
#pragma unroll 1
    for (int jj = 0; jj < KNN; jj += 2) {
        sh1[w][0][lane] = fmaxf(basec + g0, 0.f);
        sh1[w][1][lane] = fmaxf(basec + g1, 0.f);
        int2 jn;
        bool more = (jj + 2 < KNN);
        if (more) jn = *reinterpret_cast<const int2*>(ip + jj + 2);
        __syncthreads();
        if (more) {
            g0 = G[(size_t)jn.x*64 + lane];
            g1 = G[(size_t)jn.y*64 + lane];
        }
        float h20 = bbc, h21 = bbc;
#pragma unroll
        for (int k = 0; k < 64; k += 4) {
            float4 a = *reinterpret_cast<const float4*>(&sh1[w][0][k]);
            float4 b = *reinterpret_cast<const float4*>(&sh1[w][1][k]);
            h20 += a.x*wbc[k] + a.y*wbc[k+1] + a.z*wbc[k+2] + a.w*wbc[k+3];
            h21 += b.x*wbc[k] + b.y*wbc[k+1] + b.z*wbc[k+2] + b.w*wbc[k+3];
        }
        maxv = fmaxf(maxv, fmaxf(h20, h21));
        __syncthreads();
    }
    fout[(size_t)n * out_stride + lane] = maxv;
}

// ---------------- weight split: w[K][N] fp32 -> hi/lo bf16 transposed [N][K] ----------------
__global__ void wsplit_kernel(const float* __restrict__ w, int K, int N,
                              ushort* __restrict__ hi, ushort* __restrict__ lo, int total) {
    int i = blockIdx.x * 256 + threadIdx.x;
    if (i >= total) return;
    int n = i / K, k = i - n*K;
    float x = w[(size_t)k * N + n];
    ushort h = f2bf(x);
    hi[i] = h;
    lo[i] = f2bf(x - bf2f(h));
}

// ---------------- split-bf16 MFMA GEMM: C[M][N] = act(A[M][K] @ W + bias) ----------------
template<bool RELU>
__global__ __launch_bounds__(256) void mlp_gemm_kernel(
    const float* __restrict__ A, int lda, int K,
    const ushort* __restrict__ Bhi, const ushort* __restrict__ Blo,
    const float* __restrict__ bias, float* __restrict__ C, int N)
{
    __shared__ __align__(16) ushort sAh[64*40];
    __shared__ __align__(16) ushort sAl[64*40];
    __shared__ __align__(16) ushort sBh[64*40];
    __shared__ __align__(16) ushort sBl[64*40];
    int t = threadIdx.x;
    int row0 = blockIdx.x * 64;
    int n0   = blockIdx.y * 64;
    int r = t >> 2, sg = (t & 3) * 8;
    int lane = t & 63, w = t >> 6;
    int wr = w & 1, wc = w >> 1;
    int fr = lane & 15, fk = (lane >> 4) * 8;

    f32x4 acc00 = {0.f,0.f,0.f,0.f}, acc01 = {0.f,0.f,0.f,0.f};
    f32x4 acc10 = {0.f,0.f,0.f,0.f}, acc11 = {0.f,0.f,0.f,0.f};

    const int nk = K / 32;
#pragma unroll 1
    for (int kc = 0; kc < nk; ++kc) {
        int k0 = kc * 32;
        const float* ap = A + (size_t)(row0 + r) * lda + k0 + sg;
        float4 av0 = *reinterpret_cast<const float4*>(ap);
        float4 av1 = *reinterpret_cast<const float4*>(ap + 4);
        float av[8] = {av0.x,av0.y,av0.z,av0.w,av1.x,av1.y,av1.z,av1.w};
        uint ph[4], pl[4];
#pragma unroll
        for (int i = 0; i < 4; ++i) {
            ushort h0 = f2bf(av[2*i]);
            ushort l0 = f2bf(av[2*i]   - bf2f(h0));
            ushort h1 = f2bf(av[2*i+1]);
            ushort l1 = f2bf(av[2*i+1] - bf2f(h1));
            ph[i] = (uint)h0 | ((uint)h1 << 16);
            pl[i] = (uint)l0 | ((uint)l1 << 16);
        }
        uint4 bh = *reinterpret_cast<const uint4*>(Bhi + (size_t)(n0 + r) * K + k0 + sg);
        uint4 bl = *reinterpret_cast<const uint4*>(Blo + (size_t)(n0 + r) * K + k0 + sg);
        __syncthreads();
        *reinterpret_cast<uint4*>(&sAh[r*40 + sg]) = make_uint4(ph[0],ph[1],ph[2],ph[3]);
        *reinterpret_cast<uint4*>(&sAl[r*40 + sg]) = make_uint4(pl[0],pl[1],pl[2],pl[3]);
        *reinterpret_cast<uint4*>(&sBh[r*40 + sg]) = bh;
        *reinterpret_cast<uint4*>(&sBl[r*40 + sg]) = bl;
        __syncthreads();

        bf16x8 a0h = *reinterpret_cast<const bf16x8*>(&sAh[(wr*32 + fr)*40 + fk]);
        bf16x8 a1h = *reinterpret_cast<const bf16x8*>(&sAh[(wr*32 + 16 + fr)*40 + fk]);
        bf16x8 a0l = *reinterpret_cast<const bf16x8*>(&sAl[(wr*32 + fr)*40 + fk]);
        bf16x8 a1l = *reinterpret_cast<const bf16x8*>(&sAl[(wr*32 + 16 + fr)*40 + fk]);
        bf16x8 b0h = *reinterpret_cast<const bf16x8*>(&sBh[(wc*32 + fr)*40 + fk]);
        bf16x8 b1h = *reinterpret_cast<const bf16x8*>(&sBh[(wc*32 + 16 + fr)*40 + fk]);
        bf16x8 b0l = *reinterpret_cast<const bf16x8*>(&sBl[(wc*32 + fr)*40 + fk]);
        bf16x8 b1l = *reinterpret_cast<const bf16x8*>(&sBl[(wc*32 + 16 + fr)*40 + fk]);

        acc00 = __builtin_amdgcn_mfma_f32_16x16x32_bf16(a0h, b0h, acc00, 0, 0, 0);
        acc00 = __builtin_amdgcn_mfma_f32_16x16x32_bf16(a0h, b0l, acc00, 0, 0, 0);
        acc00 = __builtin_amdgcn_mfma_f32_16x16x32_bf16(a0l, b0h, acc00, 0, 0, 0);
        acc01 = __builtin_amdgcn_mfma_f32_16x16x32_bf16(a0h, b1h, acc01, 0, 0, 0);
        acc01 = __builtin_amdgcn_mfma_f32_16x16x32_bf16(a0h, b1l, acc01, 0, 0, 0);
        acc01 = __builtin_amdgcn_mfma_f32_16x16x32_bf16(a0l, b1h, acc01, 0, 0, 0);
        acc10 = __builtin_amdgcn_mfma_f32_16x16x32_bf16(a1h, b0h, acc10, 0, 0, 0);
        acc10 = __builtin_amdgcn_mfma_f32_16x16x32_bf16(a1h, b0l, acc10, 0, 0, 0);
        acc10 = __builtin_amdgcn_mfma_f32_16x16x32_bf16(a1l, b0h, acc10, 0, 0, 0);
        acc11 = __builtin_amdgcn_mfma_f32_16x16x32_bf16(a1h, b1h, acc11, 0, 0, 0);
        acc11 = __builtin_amdgcn_mfma_f32_16x16x32_bf16(a1h, b1l, acc11, 0, 0, 0);
        acc11 = __builtin_amdgcn_mfma_f32_16x16x32_bf16(a1l, b1h, acc11, 0, 0, 0);
    }

    int orow = row0 + wr*32 + (lane >> 4)*4;
    int ocol = n0 + wc*32 + fr;
    float bc0 = bias[ocol];
    float bc1 = bias[ocol + 16];
#pragma unroll
    for (int j = 0; j < 4; ++j) {
        float v00 = acc00[j] + bc0;
        float v01 = acc01[j] + bc1;
        float v10 = acc10[j] + bc0;
        float v11 = acc11[j] + bc1;
        if (RELU) {
            v00 = fmaxf(v00, 0.f); v01 = fmaxf(v01, 0.f);
            v10 = fmaxf(v10, 0.f); v11 = fmaxf(v11, 0.f);
        }
        C[(size_t)(orow + j)*N + ocol]           = v00;
        C[(size_t)(orow + j)*N + ocol + 16]      = v01;
        C[(size_t)(orow + 16 + j)*N + ocol]      = v10;
        C[(size_t)(orow + 16 + j)*N + ocol + 16] = v11;
    }
}

// ---------------- fallback fp32 head (only if ws too small for MFMA path) ----------------
__global__ __launch_bounds__(256) void head_kernel(const float* __restrict__ feat,
                            const float* __restrict__ hw1, const float* __restrict__ hb1,
                            const float* __restrict__ hw2, const float* __restrict__ hb2,
                            const float* __restrict__ hw3, const float* __restrict__ hb3,
                            float* __restrict__ out) {
    __shared__ float smem[16384];
    float* sfeat = smem;
    float* sh1   = smem + 6144;
    int t = threadIdx.x;
    int row0 = blockIdx.x * 32;

    for (int i = t; i < 32*192; i += 256) sfeat[i] = feat[(size_t)row0*192 + i];
    __syncthreads();

    int c4 = t & 127, rh = t >> 7;
    float4 acc2[16];
    {
        float4 b = *reinterpret_cast<const float4*>(&hb2[4*c4]);
#pragma unroll
        for (int i = 0; i < 16; ++i) acc2[i] = b;
    }
    int c1 = t & 63, rg = t >> 6;

    for (int chunk = 0; chunk < 8; ++chunk) {
        int k0 = chunk * 128;
        float acc1a[8], acc1b[8];
        {
            float ba_ = hb1[k0 + c1], bb_ = hb1[k0 + 64 + c1];
#pragma unroll
            for (int i = 0; i < 8; ++i) { acc1a[i] = ba_; acc1b[i] = bb_; }
        }
#pragma unroll 1
        for (int k = 0; k < 192; k += 4) {
            float wA0 = hw1[(size_t)(k+0)*1024 + k0 + c1];
            float wA1 = hw1[(size_t)(k+1)*1024 + k0 + c1];
            float wA2 = hw1[(size_t)(k+2)*1024 + k0 + c1];
            float wA3 = hw1[(size_t)(k+3)*1024 + k0 + c1];
            float wB0 = hw1[(size_t)(k+0)*1024 + k0 + 64 + c1];
            float wB1 = hw1[(size_t)(k+1)*1024 + k0 + 64 + c1];
            float wB2 = hw1[(size_t)(k+2)*1024 + k0 + 64 + c1];
            float wB3 = hw1[(size_t)(k+3)*1024 + k0 + 64 + c1];
#pragma unroll
            for (int i = 0; i < 8; ++i) {
                float4 fv = *reinterpret_cast<const float4*>(&sfeat[(rg + 4*i)*192 + k]);
                acc1a[i] += fv.x*wA0 + fv.y*wA1 + fv.z*wA2 + fv.w*wA3;
                acc1b[i] += fv.x*wB0 + fv.y*wB1 + fv.z*wB2 + fv.w*wB3;
            }
        }
#pragma unroll
        for (int i = 0; i < 8; ++i) {
            sh1[(rg + 4*i)*128 + c1]      = fmaxf(acc1a[i], 0.f);
            sh1[(rg + 4*i)*128 + 64 + c1] = fmaxf(acc1b[i], 0.f);
        }
        __syncthreads();
        float4 wn[4];
#pragma unroll
        for (int q = 0; q < 4; ++q)
            wn[q] = *reinterpret_cast<const float4*>(&hw2[(size_t)(k0 + q)*512 + 4*c4]);
#pragma unroll 1
        for (int k = 0; k < 128; k += 4) {
            float4 wv[4];
#pragma unroll
            for (int q = 0; q < 4; ++q) wv[q] = wn[q];
            if (k + 4 < 128) {
#pragma unroll
                for (int q = 0; q < 4; ++q)
                    wn[q] = *reinterpret_cast<const float4*>(&hw2[(size_t)(k0 + k + 4 + q)*512 + 4*c4]);
            }
#pragma unroll
            for (int i = 0; i < 16; ++i) {
                float4 h4 = *reinterpret_cast<const float4*>(&sh1[(rh + 2*i)*128 + k]);
                acc2[i].x += h4.x*wv[0].x + h4.y*wv[1].x + h4.z*wv[2].x + h4.w*wv[3].x;
                acc2[i].y += h4.x*wv[0].y + h4.y*wv[1].y + h4.z*wv[2].y + h4.w*wv[3].y;
                acc2[i].z += h4.x*wv[0].z + h4.y*wv[1].z + h4.z*wv[2].z + h4.w*wv[3].z;
                acc2[i].w += h4.x*wv[0].w + h4.y*wv[1].w + h4.z*wv[2].w + h4.w*wv[3].w;
            }
        }
        __syncthreads();
    }
#pragma unroll
    for (int i = 0; i < 16; ++i) {
        float4 v;
        v.x = fmaxf(acc2[i].x, 0.f); v.y = fmaxf(acc2[i].y, 0.f);
        v.z = fmaxf(acc2[i].z, 0.f); v.w = fmaxf(acc2[i].w, 0.f);
        *reinterpret_cast<float4*>(&smem[(rh + 2*i)*512 + 4*c4]) = v;
    }
    __syncthreads();
    int c3 = t & 63, rg3 = t >> 6;
    float acc3a[8], acc3b[8];
    {
        float ba_ = hb3[c3], bb_ = hb3[c3 + 64];
#pragma unroll
        for (int i = 0; i < 8; ++i) { acc3a[i] = ba_; acc3b[i] = bb_; }
    }
#pragma unroll 1
    for (int k = 0; k < 512; k += 4) {
        float wA0 = hw3[(size_t)(k+0)*128 + c3];
        float wA1 = hw3[(size_t)(k+1)*128 + c3];
        float wA2 = hw3[(size_t)(k+2)*128 + c3];
        float wA3 = hw3[(size_t)(k+3)*128 + c3];
        float wB0 = hw3[(size_t)(k+0)*128 + c3 + 64];
        float wB1 = hw3[(size_t)(k+1)*128 + c3 + 64];
        float wB2 = hw3[(size_t)(k+2)*128 + c3 + 64];
        float wB3 = hw3[(size_t)(k+3)*128 + c3 + 64];
#pragma unroll
        for (int i = 0; i < 8; ++i) {
            float4 h4 = *reinterpret_cast<const float4*>(&smem[(rg3 + 4*i)*512 + k]);
            acc3a[i] += h4.x*wA0 + h4.y*wA1 + h4.z*wA2 + h4.w*wA3;
            acc3b[i] += h4.x*wB0 + h4.y*wB1 + h4.z*wB2 + h4.w*wB3;
        }
    }
#pragma unroll
    for (int i = 0; i < 8; ++i) {
        out[(size_t)(row0 + rg3 + 4*i)*128 + c3]      = acc3a[i];
        out[(size_t)(row0 + rg3 + 4*i)*128 + c3 + 64] = acc3b[i];
    }
}

extern "C" void kernel_launch(void* const* d_in, const int* in_sizes, int n_in,
                              void* d_out, int out_size, void* d_ws, size_t ws_size,
                              hipStream_t stream) {
    (void)in_sizes; (void)n_in; (void)out_size;
    const float* x   = (const float*)d_in[0];
    const float* pos = (const float*)d_in[1];
    const float* w1a = (const float*)d_in[2];
    const float* b1a = (const float*)d_in[3];
    const float* w1b = (const float*)d_in[4];
    const float* b1b = (const float*)d_in[5];
    const float* w2a = (const float*)d_in[6];
    const float* b2a = (const float*)d_in[7];
    const float* w2b = (const float*)d_in[8];
    const float* b2b = (const float*)d_in[9];
    const float* w3a = (const float*)d_in[10];
    const float* b3a = (const float*)d_in[11];
    const float* w3b = (const float*)d_in[12];
    const float* b3b = (const float*)d_in[13];
    const float* hw1 = (const float*)d_in[14];
    const float* hb1 = (const float*)d_in[15];
    const float* hw2 = (const float*)d_in[16];
    const float* hb2 = (const float*)d_in[17];
    const float* hw3 = (const float*)d_in[18];
    const float* hb3 = (const float*)d_in[19];
    float* out = (float*)d_out;

    float* ws = (float*)d_ws;
    float* x0   = ws;                                  // 98304
    float* feat = ws + 98304;                          // 3145728
    float* d2b  = ws + 3244032;                        // 16384
    int*   idxb = (int*)(ws + 3260416);                // 491520
    float* G    = ws + 3751936;                        // 1048576
    ushort* w1h = (ushort*)(ws + 4800512);
    ushort* w1l = (ushort*)(ws + 4898816);
    ushort* w2h = (ushort*)(ws + 4997120);
    ushort* w2l = (ushort*)(ws + 5259264);
    ushort* w3h = (ushort*)(ws + 5521408);
    ushort* w3l = (ushort*)(ws + 5554176);
    const size_t base_units = 5586944;

    int ns = 0;
    {
        const int cands[5] = {1, 2, 4, 8, 16};
        for (int ci = 0; ci < 5; ++ci) {
            int c = cands[ci];
            size_t need = (base_units + (size_t)(NPTS / c) * 1536) * 4;
            if (need <= ws_size) { ns = c; break; }
        }
    }

    concat_kernel<<<NPTS/256, 256, 0, stream>>>(x, pos, x0);

    d2_kernel<6><<<NPTS/256, 256, 0, stream>>>(x0, 6, d2b);
    knn_reg_kernel<6><<<NPTS/16, 256, 0, stream>>>(x0, 6, d2b, idxb);
    gmat_kernel<6><<<NPTS/64, 256, 0, stream>>>(x0, 6, w1a, G);
    edgeconv2_kernel<6><<<NPTS/4, 256, 0, stream>>>(x0, 6, G, idxb, w1a, b1a, w1b, b1b, feat, 192);

    d2_kernel<64><<<NPTS/256, 256, 0, stream>>>(feat, 192, d2b);
    knn_reg_kernel<64><<<NPTS/16, 256, 0, stream>>>(feat, 192, d2b, idxb);
    gmat_kernel<64><<<NPTS/64, 256, 0, stream>>>(feat, 192, w2a, G);
    edgeconv2_kernel<64><<<NPTS/4, 256, 0, stream>>>(feat, 192, G, idxb, w2a, b2a, w2b, b2b, feat + 64, 192);

    d2_kernel<64><<<NPTS/256, 256, 0, stream>>>(feat + 64, 192, d2b);
    knn_reg_kernel<64><<<NPTS/16, 256, 0, stream>>>(feat + 64, 192, d2b, idxb);
    gmat_kernel<64><<<NPTS/64, 256, 0, stream>>>(feat + 64, 192, w3a, G);
    edgeconv2_kernel<64><<<NPTS/4, 256, 0, stream>>>(feat + 64, 192, G, idxb, w3a, b3a, w3b, b3b, feat + 128, 192);

    if (ns > 0) {
        wsplit_kernel<<<(192*1024 + 255)/256, 256, 0, stream>>>(hw1, 192, 1024, w1h, w1l, 192*1024);
        wsplit_kernel<<<(1024*512 + 255)/256, 256, 0, stream>>>(hw2, 1024, 512, w2h, w2l, 1024*512);
        wsplit_kernel<<<(512*128 + 255)/256, 256, 0, stream>>>(hw3, 512, 128, w3h, w3l, 512*128);

        int Ms = NPTS / ns;
        float* h1 = ws + base_units;
        float* h2 = h1 + (size_t)Ms * 1024;
        for (int s = 0; s < ns; ++s) {
            const float* As = feat + (size_t)s * Ms * 192;
            float* outs = out + (size_t)s * Ms * 128;
            mlp_gemm_kernel<true ><<<dim3(Ms/64, 1024/64), 256, 0, stream>>>(As, 192, 192, w1h, w1l, hb1, h1, 1024);
            mlp_gemm_kernel<true ><<<dim3(Ms/64,  512/64), 256, 0, stream>>>(h1, 1024, 1024, w2h, w2l, hb2, h2, 512);
            mlp_gemm_kernel<false><<<dim3(Ms/64,  128/64), 256, 0, stream>>>(h2, 512, 512, w3h, w3l, hb3, outs, 128);
        }
    } else {
        head_kernel<<<NPTS/32, 256, 0, stream>>>(feat, hw1, hb1, hw2, hb2, hw3, hb3, out);
    }
}